// Round 16
// baseline (228.276 us; speedup 1.0000x reference)
//
#include <hip/hip_runtime.h>

#define CC 128
#define SS 4096
#define L2E 1.44269504f

typedef _Float16 f16;
typedef f16 f16x8 __attribute__((ext_vector_type(8)));
typedef __fp16 fp16x2 __attribute__((ext_vector_type(2)));
typedef float f32x4 __attribute__((ext_vector_type(4)));

struct PArg { const float *x, *w, *b, *sc, *bb, *bm, *bv; f16* out; };

// ---------------------------------------------------------------- proj (MFMA, prep fused)
// grid (256, 3): y=p, x = b*64 + st. p=0,1 -> [B][S][C]; p=2 -> [B][C][S].
__global__ __launch_bounds__(256) void projk(PArg A0, PArg A1, PArg A2) {
    const int p = blockIdx.y;
    PArg A = (p == 0) ? A0 : ((p == 1) ? A1 : A2);
    const int bx = blockIdx.x;
    const int b  = bx >> 6;
    const int s0 = (bx & 63) * 64;
    const int tid = threadIdx.x;
    const int w = tid >> 6, lane = tid & 63;
    const int n = lane & 15, g = lane >> 4;

    __shared__ f16 Xl[64][136];                 // X^T tile [s][c]
    __shared__ f16 Wl[128][136];                // Weff [o][c], aliased as Yl
    f16* Yl = &Wl[0][0];

    // stage X: fp32 [c][s] -> f16 [s][c]
#pragma unroll
    for (int i = 0; i < 8; ++i) {
        int vi = tid + i * 256;                 // 0..2047
        int c = vi >> 4, sq = (vi & 15) * 4;
        float4 v = *(const float4*)(A.x + ((size_t)b * CC + c) * SS + s0 + sq);
        Xl[sq + 0][c] = (f16)v.x; Xl[sq + 1][c] = (f16)v.y;
        Xl[sq + 2][c] = (f16)v.z; Xl[sq + 3][c] = (f16)v.w;
    }
    // stage W (fp32 -> f16, fold inv computed directly from global)
#pragma unroll
    for (int i = 0; i < 8; ++i) {
        int vi = tid + i * 256;
        int o = vi >> 4, cq = (vi & 15) * 8;
        float iv = A.sc[o] * rsqrtf(A.bv[o] + 1e-5f);
        const float* wp = A.w + o * CC + cq;
        float4 a = *(const float4*)wp;
        float4 b4 = *(const float4*)(wp + 4);
        union { f16 h[8]; uint4 u; } pk;
        pk.h[0] = (f16)(a.x * iv);  pk.h[1] = (f16)(a.y * iv);
        pk.h[2] = (f16)(a.z * iv);  pk.h[3] = (f16)(a.w * iv);
        pk.h[4] = (f16)(b4.x * iv); pk.h[5] = (f16)(b4.y * iv);
        pk.h[6] = (f16)(b4.z * iv); pk.h[7] = (f16)(b4.w * iv);
        *(uint4*)&Wl[o][cq] = pk.u;
    }
    __syncthreads();

    if (p < 2) {
        // D[m=o][n=s]: A=Weff, B=X. Wave w: o in [w*32, w*32+32), all 64 s.
        f32x4 acc[2][4];
#pragma unroll
        for (int mt = 0; mt < 2; ++mt)
#pragma unroll
            for (int nt = 0; nt < 4; ++nt) acc[mt][nt] = (f32x4){0.f, 0.f, 0.f, 0.f};
#pragma unroll
        for (int ks = 0; ks < 4; ++ks) {
            f16x8 af[2], bf[4];
#pragma unroll
            for (int mt = 0; mt < 2; ++mt) af[mt] = *(const f16x8*)&Wl[w * 32 + mt * 16 + n][ks * 32 + g * 8];
#pragma unroll
            for (int nt = 0; nt < 4; ++nt) bf[nt] = *(const f16x8*)&Xl[nt * 16 + n][ks * 32 + g * 8];
#pragma unroll
            for (int mt = 0; mt < 2; ++mt)
#pragma unroll
                for (int nt = 0; nt < 4; ++nt)
                    acc[mt][nt] = __builtin_amdgcn_mfma_f32_16x16x32_f16(af[mt], bf[nt], acc[mt][nt], 0, 0, 0);
        }
        __syncthreads();
#pragma unroll
        for (int mt = 0; mt < 2; ++mt) {
            float ebr[4];
#pragma unroll
            for (int r = 0; r < 4; ++r) {
                int o = w * 32 + mt * 16 + g * 4 + r;
                float iv = A.sc[o] * rsqrtf(A.bv[o] + 1e-5f);
                ebr[r] = (A.b[o] - A.bm[o]) * iv + A.bb[o];
            }
#pragma unroll
            for (int nt = 0; nt < 4; ++nt) {
                union { f16 h[4]; uint2 u; } pk;
#pragma unroll
                for (int r = 0; r < 4; ++r) {
                    float y = acc[mt][nt][r] + ebr[r];
                    y = (y > 0.f) ? y : (__expf(y) - 1.f);
                    pk.h[r] = (f16)y;
                }
                *(uint2*)&Yl[(nt * 16 + n) * 136 + w * 32 + mt * 16 + g * 4] = pk.u;
            }
        }
        __syncthreads();
#pragma unroll
        for (int i = 0; i < 4; ++i) {
            int vi = tid + i * 256;
            int s = vi >> 4, cl = (vi & 15) * 8;
            *(uint4*)&A.out[((size_t)b * SS + s0 + s) * CC + cl] = *(const uint4*)&Yl[s * 136 + cl];
        }
    } else {
        // D[m=s][n=o]: A=X, B=Weff. Wave w: s in [w*16, w*16+16), all 128 o.
        f32x4 acc[8];
#pragma unroll
        for (int nt = 0; nt < 8; ++nt) acc[nt] = (f32x4){0.f, 0.f, 0.f, 0.f};
#pragma unroll
        for (int ks = 0; ks < 4; ++ks) {
            f16x8 af = *(const f16x8*)&Xl[w * 16 + n][ks * 32 + g * 8];
#pragma unroll
            for (int nt = 0; nt < 8; ++nt) {
                f16x8 bf = *(const f16x8*)&Wl[nt * 16 + n][ks * 32 + g * 8];
                acc[nt] = __builtin_amdgcn_mfma_f32_16x16x32_f16(af, bf, acc[nt], 0, 0, 0);
            }
        }
        __syncthreads();
#pragma unroll
        for (int nt = 0; nt < 8; ++nt) {
            int o = nt * 16 + n;
            float iv = A.sc[o] * rsqrtf(A.bv[o] + 1e-5f);
            float ebc = (A.b[o] - A.bm[o]) * iv + A.bb[o];
            union { f16 h[4]; uint2 u; } pk;
#pragma unroll
            for (int r = 0; r < 4; ++r) {
                float y = acc[nt][r] + ebc;
                y = (y > 0.f) ? y : (__expf(y) - 1.f);
                pk.h[r] = (f16)y;
            }
            *(uint2*)&Yl[(nt * 16 + n) * 136 + w * 16 + g * 4] = pk.u;   // Yl[o][s]
        }
        __syncthreads();
#pragma unroll
        for (int i = 0; i < 4; ++i) {
            int vi = tid + i * 256;
            int o = vi >> 3, sl = (vi & 7) * 8;
            *(uint4*)&A.out[((size_t)b * CC + o) * SS + s0 + sl] = *(const uint4*)&Yl[o * 136 + sl];
        }
    }
}

// ---------------------------------------------------------------- attention
// R14 double-buffered structure + VALU trims: lazy rescale (skip when max
// unchanged: exp2(0)==1 exactly), packed f32->f16 cvt, vector rescale.
// grid 1024: kh=bx&7, b=(bx>>3)&3, qt=bx>>5 (XCD swizzle). 256 threads (4 waves);
// wave owns 32 q of a 128-q tile. 512 keys/block, 16 steps of 32 keys.
__global__ __launch_bounds__(256, 3) void attnk(
    const f16* __restrict__ Qt, const f16* __restrict__ Kt, const f16* __restrict__ Vt,
    f16* __restrict__ Op, float* __restrict__ Ml)
{
    const int tid = threadIdx.x;
    const int bx = blockIdx.x;
    const int kh = bx & 7;
    const int b  = (bx >> 3) & 3;
    const int qt = bx >> 5;
    const int q0 = qt * 128;
    const int kbeg = kh * 512;

    __shared__ __align__(16) char arena[48128];
    const int w = tid >> 6, lane = tid & 63;
    const int n = lane & 15, g = lane >> 4;
    f16 (*Pw)[40] = (f16(*)[40])(arena + 37888 + w * 2560);  // wave-private P [32 q][32 key]

    // Q B-frags from global: B[k=c][n=q], q = q0 + w*32 + qt2*16 + n
    f16x8 qf[2][4];
    {
        const f16* Qb = Qt + ((size_t)b * SS + q0 + w * 32) * CC;
#pragma unroll
        for (int qt2 = 0; qt2 < 2; ++qt2)
#pragma unroll
            for (int ks = 0; ks < 4; ++ks)
                qf[qt2][ks] = *(const f16x8*)&Qb[(qt2 * 16 + n) * CC + ks * 32 + g * 8];
    }

    f32x4 oacc[8][2];                            // O^T: c = mtc*16+g*4+r, q = w*32+qt2*16+n
#pragma unroll
    for (int mtc = 0; mtc < 8; ++mtc)
#pragma unroll
        for (int qt2 = 0; qt2 < 2; ++qt2) oacc[mtc][qt2] = (f32x4){0.f, 0.f, 0.f, 0.f};
    float mreg[2] = {-1e30f, -1e30f}, lsum[2] = {0.f, 0.f};

    // staging offsets (2 uint4 each for K and V)
    const int rk0 = tid >> 4,        ck0 = (tid & 15) * 8;
    const int rk1 = (tid + 256) >> 4, ck1 = ((tid + 256) & 15) * 8;
    const int rv0 = tid >> 2,        cv0 = (tid & 3) * 8;
    const int rv1 = (tid + 256) >> 2, cv1 = ((tid + 256) & 3) * 8;

    // prologue: stage tile 0 into buffer 0
    {
        f16 (*Kl)[136] = (f16(*)[136])(arena);
        f16 (*Vl)[40]  = (f16(*)[40])(arena + 17408);
        *(uint4*)&Kl[rk0][ck0] = *(const uint4*)&Kt[((size_t)b * SS + kbeg + rk0) * CC + ck0];
        *(uint4*)&Kl[rk1][ck1] = *(const uint4*)&Kt[((size_t)b * SS + kbeg + rk1) * CC + ck1];
        *(uint4*)&Vl[rv0][cv0] = *(const uint4*)&Vt[((size_t)b * CC + rv0) * SS + kbeg + cv0];
        *(uint4*)&Vl[rv1][cv1] = *(const uint4*)&Vt[((size_t)b * CC + rv1) * SS + kbeg + cv1];
    }

    for (int kt = 0; kt < 16; ++kt) {
        const int cur = kt & 1;
        f16 (*Kl)[136] = (f16(*)[136])(arena + cur * 8704);
        f16 (*Vl)[40]  = (f16(*)[40])(arena + 17408 + cur * 10240);
        f16 (*Kn)[136] = (f16(*)[136])(arena + (1 - cur) * 8704);
        f16 (*Vn)[40]  = (f16(*)[40])(arena + 17408 + (1 - cur) * 10240);

        __syncthreads();                        // buf[cur] writes done; buf[1-cur] reads done

        // issue next-tile loads (land during phase A)
        uint4 nk0, nk1, nv0, nv1;
        if (kt < 15) {
            const int k1 = kbeg + (kt + 1) * 32;
            nk0 = *(const uint4*)&Kt[((size_t)b * SS + k1 + rk0) * CC + ck0];
            nk1 = *(const uint4*)&Kt[((size_t)b * SS + k1 + rk1) * CC + ck1];
            nv0 = *(const uint4*)&Vt[((size_t)b * CC + rv0) * SS + k1 + cv0];
            nv1 = *(const uint4*)&Vt[((size_t)b * CC + rv1) * SS + k1 + cv1];
        }

        // phase A: S^T[key][q] = K.Q^T  (A=K, B=Q). key = kt2*16+g*4+r, q = w*32+qt2*16+n
        f32x4 sacc[2][2];
#pragma unroll
        for (int kt2 = 0; kt2 < 2; ++kt2)
#pragma unroll
            for (int qt2 = 0; qt2 < 2; ++qt2) sacc[kt2][qt2] = (f32x4){0.f, 0.f, 0.f, 0.f};
#pragma unroll
        for (int ks = 0; ks < 4; ++ks) {
            f16x8 kf[2];
#pragma unroll
            for (int kt2 = 0; kt2 < 2; ++kt2) kf[kt2] = *(const f16x8*)&Kl[kt2 * 16 + n][ks * 32 + g * 8];
#pragma unroll
            for (int kt2 = 0; kt2 < 2; ++kt2)
#pragma unroll
                for (int qt2 = 0; qt2 < 2; ++qt2)
                    sacc[kt2][qt2] = __builtin_amdgcn_mfma_f32_16x16x32_f16(kf[kt2], qf[qt2][ks], sacc[kt2][qt2], 0, 0, 0);
        }

        // stage next tile into the other buffer
        if (kt < 15) {
            *(uint4*)&Kn[rk0][ck0] = nk0;
            *(uint4*)&Kn[rk1][ck1] = nk1;
            *(uint4*)&Vn[rv0][cv0] = nv0;
            *(uint4*)&Vn[rv1][cv1] = nv1;
        }

        // online softmax per q-column (lane holds 8 keys of col q; lanes n+16k complete it)
        float al[2], rsv[2];
#pragma unroll
        for (int qt2 = 0; qt2 < 2; ++qt2) {
            float v = sacc[0][qt2][0];
#pragma unroll
            for (int kt2 = 0; kt2 < 2; ++kt2)
#pragma unroll
                for (int r = 0; r < 4; ++r) v = fmaxf(v, sacc[kt2][qt2][r]);
            v = fmaxf(v, __shfl_xor(v, 16));
            v = fmaxf(v, __shfl_xor(v, 32));
            float mn = fmaxf(mreg[qt2], v);
            al[qt2] = exp2f((mreg[qt2] - mn) * L2E);   // == 1.0 exactly if max unchanged
            mreg[qt2] = mn;
            float rs = 0.f;
#pragma unroll
            for (int kt2 = 0; kt2 < 2; ++kt2) {
                float p0 = exp2f((sacc[kt2][qt2][0] - mn) * L2E);
                float p1 = exp2f((sacc[kt2][qt2][1] - mn) * L2E);
                float p2 = exp2f((sacc[kt2][qt2][2] - mn) * L2E);
                float p3 = exp2f((sacc[kt2][qt2][3] - mn) * L2E);
                rs += (p0 + p1) + (p2 + p3);
                union { fp16x2 h2[2]; uint2 u; } pk;
                pk.h2[0] = __builtin_amdgcn_cvt_pkrtz(p0, p1);
                pk.h2[1] = __builtin_amdgcn_cvt_pkrtz(p2, p3);
                *(uint2*)&Pw[qt2 * 16 + n][kt2 * 16 + g * 4] = pk.u;
            }
            rsv[qt2] = rs;
        }
        // lazy rescale: skip the 64 fmuls when no lane's max moved this step
        if (__any((al[0] < 1.f) || (al[1] < 1.f))) {
#pragma unroll
            for (int mtc = 0; mtc < 8; ++mtc)
#pragma unroll
                for (int qt2 = 0; qt2 < 2; ++qt2) oacc[mtc][qt2] *= al[qt2];
            lsum[0] = lsum[0] * al[0] + rsv[0];
            lsum[1] = lsum[1] * al[1] + rsv[1];
        } else {
            lsum[0] += rsv[0];
            lsum[1] += rsv[1];
        }

        // phase B: O^T[c][q] += V.P^T  (A=V[c][key], B=P[q][key]; one K=32 chunk)
        {
            f16x8 pf[2];
#pragma unroll
            for (int qt2 = 0; qt2 < 2; ++qt2) pf[qt2] = *(const f16x8*)&Pw[qt2 * 16 + n][g * 8];
#pragma unroll
            for (int mtc = 0; mtc < 8; ++mtc) {
                f16x8 vf = *(const f16x8*)&Vl[mtc * 16 + n][g * 8];
#pragma unroll
                for (int qt2 = 0; qt2 < 2; ++qt2)
                    oacc[mtc][qt2] = __builtin_amdgcn_mfma_f32_16x16x32_f16(vf, pf[qt2], oacc[mtc][qt2], 0, 0, 0);
            }
        }
    }

    // final l reduction over g-lanes
    float lreg[2];
#pragma unroll
    for (int qt2 = 0; qt2 < 2; ++qt2) {
        float s = lsum[qt2];
        s += __shfl_xor(s, 16);
        s += __shfl_xor(s, 32);
        lreg[qt2] = s;
    }

    const int pidx = (b * 32 + qt) * 8 + kh;
    if (g == 0) {
        float* MlW = Ml + (size_t)pidx * 256;
#pragma unroll
        for (int qt2 = 0; qt2 < 2; ++qt2) {
            int q = w * 32 + qt2 * 16 + n;
            MlW[q]       = mreg[qt2];
            MlW[128 + q] = lreg[qt2];
        }
    }

    // epilogue: transpose O^T frags through LDS (reuse arena), coalesced store
    __syncthreads();                            // all phase-B reads done
    f16 (*S2)[136] = (f16(*)[136])arena;        // [128 c][128 q] = 34816 B (fits arena)
#pragma unroll
    for (int mtc = 0; mtc < 8; ++mtc)
#pragma unroll
        for (int qt2 = 0; qt2 < 2; ++qt2)
#pragma unroll
            for (int r = 0; r < 4; ++r)
                S2[mtc * 16 + g * 4 + r][w * 32 + qt2 * 16 + n] = (f16)oacc[mtc][qt2][r];
    __syncthreads();
    f16* OpW = Op + (size_t)pidx * 16384;
#pragma unroll
    for (int i = 0; i < 8; ++i) {
        int vi = tid + i * 256;                 // 0..2047
        int c = vi >> 4, qq = (vi & 15) * 8;
        *(uint4*)&OpW[c * 128 + qq] = *(const uint4*)&S2[c][qq];
    }
}

// ---------------------------------------------------------------- merge (8 partials)
__global__ __launch_bounds__(256) void mrgk(
    const f16* __restrict__ Op, const float* __restrict__ Ml,
    const float* __restrict__ xv, const float* __restrict__ gp, const float* __restrict__ bp,
    float* __restrict__ out)
{
    const int bx = blockIdx.x;                 // (b*32+qt)*4 + cg
    const int cg = bx & 3, bqt = bx >> 2;
    const int b = bqt >> 5, qt = bqt & 31;
    const int tid = threadIdx.x;
    const int q = tid & 127, hf = tid >> 7;

    const float* ml = Ml + (size_t)bqt * 8 * 256;
    float m = -1e30f;
#pragma unroll
    for (int k2 = 0; k2 < 8; ++k2) m = fmaxf(m, ml[k2 * 256 + q]);
    float wt[8], tot = 0.f;
#pragma unroll
    for (int k2 = 0; k2 < 8; ++k2) {
        wt[k2] = exp2f((ml[k2 * 256 + q] - m) * L2E);
        tot += wt[k2] * ml[k2 * 256 + 128 + q];
    }
    float inv = 1.f / tot;
    float gm = gp[0], bb = bp[0];

    const f16* O = Op + (size_t)bqt * 8 * 16384;
#pragma unroll 2
    for (int i = 0; i < 16; ++i) {
        int c = cg * 32 + hf * 16 + i;
        float o = 0.f;
#pragma unroll
        for (int k2 = 0; k2 < 8; ++k2) o += wt[k2] * (float)O[k2 * 16384 + c * 128 + q];
        o *= inv;
        size_t idx = ((size_t)(b * CC + c)) * SS + qt * 128 + q;
        out[idx] = gm * o + bb * xv[idx];
    }
}

// ---------------------------------------------------------------- launcher
extern "C" void kernel_launch(void* const* d_in, const int* in_sizes, int n_in,
                              void* d_out, int out_size, void* d_ws, size_t ws_size,
                              hipStream_t stream) {
    (void)in_sizes; (void)n_in; (void)out_size; (void)ws_size;

    const size_t TEN = (size_t)4 * SS * CC;          // 2,097,152
    f16* Qt = (f16*)d_ws;                            // 4 MB
    f16* Kt = Qt + TEN;                              // 4 MB
    f16* Vt = Kt + TEN;                              // 4 MB (channel-major)
    f16* Op = Vt + TEN;                              // 1024*16384 f16 = 32 MB
    float* Ml = (float*)(Op + (size_t)1024 * 16384); // 1 MB

    PArg aq = { (const float*)d_in[0], (const float*)d_in[3],  (const float*)d_in[4],
                (const float*)d_in[5], (const float*)d_in[6],  (const float*)d_in[7],
                (const float*)d_in[8],  Qt };
    PArg ak = { (const float*)d_in[1], (const float*)d_in[9],  (const float*)d_in[10],
                (const float*)d_in[11], (const float*)d_in[12], (const float*)d_in[13],
                (const float*)d_in[14], Kt };
    PArg av = { (const float*)d_in[2], (const float*)d_in[15], (const float*)d_in[16],
                (const float*)d_in[17], (const float*)d_in[18], (const float*)d_in[19],
                (const float*)d_in[20], Vt };

    hipLaunchKernelGGL(projk, dim3(256, 3), dim3(256), 0, stream, aq, ak, av);
    hipLaunchKernelGGL(attnk, dim3(1024), dim3(256), 0, stream, Qt, Kt, Vt, Op, Ml);
    hipLaunchKernelGGL(mrgk, dim3(512), dim3(256), 0, stream,
                       Op, Ml, (const float*)d_in[2], (const float*)d_in[21],
                       (const float*)d_in[22], (float*)d_out);
}

// Round 17
// 186.250 us; speedup vs baseline: 1.2256x; 1.2256x over previous
//
#include <hip/hip_runtime.h>

#define CC 128
#define SS 4096
#define L2E 1.44269504f

typedef _Float16 f16;
typedef f16 f16x8 __attribute__((ext_vector_type(8)));
typedef float f32x4 __attribute__((ext_vector_type(4)));

struct PArg { const float *x, *w, *b, *sc, *bb, *bm, *bv; f16* out; };

// ---------------------------------------------------------------- proj (MFMA, prep fused)
// grid (256, 3): y=p, x = b*64 + st. p=0,1 -> [B][S][C]; p=2 -> [B][C][S].
__global__ __launch_bounds__(256) void projk(PArg A0, PArg A1, PArg A2) {
    const int p = blockIdx.y;
    PArg A = (p == 0) ? A0 : ((p == 1) ? A1 : A2);
    const int bx = blockIdx.x;
    const int b  = bx >> 6;
    const int s0 = (bx & 63) * 64;
    const int tid = threadIdx.x;
    const int w = tid >> 6, lane = tid & 63;
    const int n = lane & 15, g = lane >> 4;

    __shared__ f16 Xl[64][136];                 // X^T tile [s][c]
    __shared__ f16 Wl[128][136];                // Weff [o][c], aliased as Yl
    f16* Yl = &Wl[0][0];

    // stage X: fp32 [c][s] -> f16 [s][c]
#pragma unroll
    for (int i = 0; i < 8; ++i) {
        int vi = tid + i * 256;                 // 0..2047
        int c = vi >> 4, sq = (vi & 15) * 4;
        float4 v = *(const float4*)(A.x + ((size_t)b * CC + c) * SS + s0 + sq);
        Xl[sq + 0][c] = (f16)v.x; Xl[sq + 1][c] = (f16)v.y;
        Xl[sq + 2][c] = (f16)v.z; Xl[sq + 3][c] = (f16)v.w;
    }
    // stage W (fp32 -> f16, fold inv computed directly from global)
#pragma unroll
    for (int i = 0; i < 8; ++i) {
        int vi = tid + i * 256;
        int o = vi >> 4, cq = (vi & 15) * 8;
        float iv = A.sc[o] * rsqrtf(A.bv[o] + 1e-5f);
        const float* wp = A.w + o * CC + cq;
        float4 a = *(const float4*)wp;
        float4 b4 = *(const float4*)(wp + 4);
        union { f16 h[8]; uint4 u; } pk;
        pk.h[0] = (f16)(a.x * iv);  pk.h[1] = (f16)(a.y * iv);
        pk.h[2] = (f16)(a.z * iv);  pk.h[3] = (f16)(a.w * iv);
        pk.h[4] = (f16)(b4.x * iv); pk.h[5] = (f16)(b4.y * iv);
        pk.h[6] = (f16)(b4.z * iv); pk.h[7] = (f16)(b4.w * iv);
        *(uint4*)&Wl[o][cq] = pk.u;
    }
    __syncthreads();

    if (p < 2) {
        // D[m=o][n=s]: A=Weff, B=X. Wave w: o in [w*32, w*32+32), all 64 s.
        f32x4 acc[2][4];
#pragma unroll
        for (int mt = 0; mt < 2; ++mt)
#pragma unroll
            for (int nt = 0; nt < 4; ++nt) acc[mt][nt] = (f32x4){0.f, 0.f, 0.f, 0.f};
#pragma unroll
        for (int ks = 0; ks < 4; ++ks) {
            f16x8 af[2], bf[4];
#pragma unroll
            for (int mt = 0; mt < 2; ++mt) af[mt] = *(const f16x8*)&Wl[w * 32 + mt * 16 + n][ks * 32 + g * 8];
#pragma unroll
            for (int nt = 0; nt < 4; ++nt) bf[nt] = *(const f16x8*)&Xl[nt * 16 + n][ks * 32 + g * 8];
#pragma unroll
            for (int mt = 0; mt < 2; ++mt)
#pragma unroll
                for (int nt = 0; nt < 4; ++nt)
                    acc[mt][nt] = __builtin_amdgcn_mfma_f32_16x16x32_f16(af[mt], bf[nt], acc[mt][nt], 0, 0, 0);
        }
        __syncthreads();
#pragma unroll
        for (int mt = 0; mt < 2; ++mt) {
            float ebr[4];
#pragma unroll
            for (int r = 0; r < 4; ++r) {
                int o = w * 32 + mt * 16 + g * 4 + r;
                float iv = A.sc[o] * rsqrtf(A.bv[o] + 1e-5f);
                ebr[r] = (A.b[o] - A.bm[o]) * iv + A.bb[o];
            }
#pragma unroll
            for (int nt = 0; nt < 4; ++nt) {
                union { f16 h[4]; uint2 u; } pk;
#pragma unroll
                for (int r = 0; r < 4; ++r) {
                    float y = acc[mt][nt][r] + ebr[r];
                    y = (y > 0.f) ? y : (__expf(y) - 1.f);
                    pk.h[r] = (f16)y;
                }
                *(uint2*)&Yl[(nt * 16 + n) * 136 + w * 32 + mt * 16 + g * 4] = pk.u;
            }
        }
        __syncthreads();
#pragma unroll
        for (int i = 0; i < 4; ++i) {
            int vi = tid + i * 256;
            int s = vi >> 4, cl = (vi & 15) * 8;
            *(uint4*)&A.out[((size_t)b * SS + s0 + s) * CC + cl] = *(const uint4*)&Yl[s * 136 + cl];
        }
    } else {
        // D[m=s][n=o]: A=X, B=Weff. Wave w: s in [w*16, w*16+16), all 128 o.
        f32x4 acc[8];
#pragma unroll
        for (int nt = 0; nt < 8; ++nt) acc[nt] = (f32x4){0.f, 0.f, 0.f, 0.f};
#pragma unroll
        for (int ks = 0; ks < 4; ++ks) {
            f16x8 af = *(const f16x8*)&Xl[w * 16 + n][ks * 32 + g * 8];
#pragma unroll
            for (int nt = 0; nt < 8; ++nt) {
                f16x8 bf = *(const f16x8*)&Wl[nt * 16 + n][ks * 32 + g * 8];
                acc[nt] = __builtin_amdgcn_mfma_f32_16x16x32_f16(af, bf, acc[nt], 0, 0, 0);
            }
        }
        __syncthreads();
#pragma unroll
        for (int nt = 0; nt < 8; ++nt) {
            int o = nt * 16 + n;
            float iv = A.sc[o] * rsqrtf(A.bv[o] + 1e-5f);
            float ebc = (A.b[o] - A.bm[o]) * iv + A.bb[o];
            union { f16 h[4]; uint2 u; } pk;
#pragma unroll
            for (int r = 0; r < 4; ++r) {
                float y = acc[nt][r] + ebc;
                y = (y > 0.f) ? y : (__expf(y) - 1.f);
                pk.h[r] = (f16)y;
            }
            *(uint2*)&Yl[(nt * 16 + n) * 136 + w * 16 + g * 4] = pk.u;   // Yl[o][s]
        }
        __syncthreads();
#pragma unroll
        for (int i = 0; i < 4; ++i) {
            int vi = tid + i * 256;
            int o = vi >> 3, sl = (vi & 7) * 8;
            *(uint4*)&A.out[((size_t)b * CC + o) * SS + s0 + sl] = *(const uint4*)&Yl[o * 136 + sl];
        }
    }
}

// ---------------------------------------------------------------- attention
// Double-buffered LDS, ONE barrier per 32-key step. Loads issued right after the
// barrier, consumed by ds_write only after phase A (latency hidden; no register
// live-range across a barrier -> no scratch spill). XCD swizzle kept.
// grid 1024: kh=bx&7, b=(bx>>3)&3, qt=bx>>5. 256 threads (4 waves); wave owns
// 32 q of a 128-q tile. 512 keys/block, 16 steps of 32 keys. LDS 48128 -> 3 blk/CU.
// NOTE: R15/R16 added a mid-loop divergent branch (lazy rescale) — it broke the
// compiler's load scheduling (FETCH/WRITE 2x, dur +56%). Keep this loop branch-free.
__global__ __launch_bounds__(256, 3) void attnk(
    const f16* __restrict__ Qt, const f16* __restrict__ Kt, const f16* __restrict__ Vt,
    f16* __restrict__ Op, float* __restrict__ Ml)
{
    const int tid = threadIdx.x;
    const int bx = blockIdx.x;
    const int kh = bx & 7;
    const int b  = (bx >> 3) & 3;
    const int qt = bx >> 5;
    const int q0 = qt * 128;
    const int kbeg = kh * 512;

    __shared__ __align__(16) char arena[48128];
    const int w = tid >> 6, lane = tid & 63;
    const int n = lane & 15, g = lane >> 4;
    f16 (*Pw)[40] = (f16(*)[40])(arena + 37888 + w * 2560);  // wave-private P [32 q][32 key]

    // Q B-frags from global: B[k=c][n=q], q = q0 + w*32 + qt2*16 + n
    f16x8 qf[2][4];
    {
        const f16* Qb = Qt + ((size_t)b * SS + q0 + w * 32) * CC;
#pragma unroll
        for (int qt2 = 0; qt2 < 2; ++qt2)
#pragma unroll
            for (int ks = 0; ks < 4; ++ks)
                qf[qt2][ks] = *(const f16x8*)&Qb[(qt2 * 16 + n) * CC + ks * 32 + g * 8];
    }

    f32x4 oacc[8][2];                            // O^T: c = mtc*16+g*4+r, q = w*32+qt2*16+n
#pragma unroll
    for (int mtc = 0; mtc < 8; ++mtc)
#pragma unroll
        for (int qt2 = 0; qt2 < 2; ++qt2) oacc[mtc][qt2] = (f32x4){0.f, 0.f, 0.f, 0.f};
    float mreg[2] = {-1e30f, -1e30f}, lsum[2] = {0.f, 0.f};

    // staging offsets for this thread (2 uint4 each for K and V)
    const int rk0 = tid >> 4,        ck0 = (tid & 15) * 8;      // K: vi=tid
    const int rk1 = (tid + 256) >> 4, ck1 = ((tid + 256) & 15) * 8;
    const int rv0 = tid >> 2,        cv0 = (tid & 3) * 8;      // V: vi=tid
    const int rv1 = (tid + 256) >> 2, cv1 = ((tid + 256) & 3) * 8;

    // prologue: stage tile 0 into buffer 0
    {
        f16 (*Kl)[136] = (f16(*)[136])(arena);
        f16 (*Vl)[40]  = (f16(*)[40])(arena + 17408);
        *(uint4*)&Kl[rk0][ck0] = *(const uint4*)&Kt[((size_t)b * SS + kbeg + rk0) * CC + ck0];
        *(uint4*)&Kl[rk1][ck1] = *(const uint4*)&Kt[((size_t)b * SS + kbeg + rk1) * CC + ck1];
        *(uint4*)&Vl[rv0][cv0] = *(const uint4*)&Vt[((size_t)b * CC + rv0) * SS + kbeg + cv0];
        *(uint4*)&Vl[rv1][cv1] = *(const uint4*)&Vt[((size_t)b * CC + rv1) * SS + kbeg + cv1];
    }

    for (int kt = 0; kt < 16; ++kt) {
        const int cur = kt & 1;
        f16 (*Kl)[136] = (f16(*)[136])(arena + cur * 8704);
        f16 (*Vl)[40]  = (f16(*)[40])(arena + 17408 + cur * 10240);
        f16 (*Kn)[136] = (f16(*)[136])(arena + (1 - cur) * 8704);
        f16 (*Vn)[40]  = (f16(*)[40])(arena + 17408 + (1 - cur) * 10240);

        __syncthreads();                        // buf[cur] writes done; buf[1-cur] reads done

        // issue next-tile loads (land during phase A)
        uint4 nk0, nk1, nv0, nv1;
        if (kt < 15) {
            const int k1 = kbeg + (kt + 1) * 32;
            nk0 = *(const uint4*)&Kt[((size_t)b * SS + k1 + rk0) * CC + ck0];
            nk1 = *(const uint4*)&Kt[((size_t)b * SS + k1 + rk1) * CC + ck1];
            nv0 = *(const uint4*)&Vt[((size_t)b * CC + rv0) * SS + k1 + cv0];
            nv1 = *(const uint4*)&Vt[((size_t)b * CC + rv1) * SS + k1 + cv1];
        }

        // phase A: S^T[key][q] = K.Q^T  (A=K, B=Q). key = kt2*16+g*4+r, q = w*32+qt2*16+n
        f32x4 sacc[2][2];
#pragma unroll
        for (int kt2 = 0; kt2 < 2; ++kt2)
#pragma unroll
            for (int qt2 = 0; qt2 < 2; ++qt2) sacc[kt2][qt2] = (f32x4){0.f, 0.f, 0.f, 0.f};
#pragma unroll
        for (int ks = 0; ks < 4; ++ks) {
            f16x8 kf[2];
#pragma unroll
            for (int kt2 = 0; kt2 < 2; ++kt2) kf[kt2] = *(const f16x8*)&Kl[kt2 * 16 + n][ks * 32 + g * 8];
#pragma unroll
            for (int kt2 = 0; kt2 < 2; ++kt2)
#pragma unroll
                for (int qt2 = 0; qt2 < 2; ++qt2)
                    sacc[kt2][qt2] = __builtin_amdgcn_mfma_f32_16x16x32_f16(kf[kt2], qf[qt2][ks], sacc[kt2][qt2], 0, 0, 0);
        }

        // stage next tile into the other buffer (no one reads it until next barrier)
        if (kt < 15) {
            *(uint4*)&Kn[rk0][ck0] = nk0;
            *(uint4*)&Kn[rk1][ck1] = nk1;
            *(uint4*)&Vn[rv0][cv0] = nv0;
            *(uint4*)&Vn[rv1][cv1] = nv1;
        }

        // online softmax per q-column (lane holds 8 keys of col q; lanes n+16k complete it)
        float al[2];
#pragma unroll
        for (int qt2 = 0; qt2 < 2; ++qt2) {
            float v = sacc[0][qt2][0];
#pragma unroll
            for (int kt2 = 0; kt2 < 2; ++kt2)
#pragma unroll
                for (int r = 0; r < 4; ++r) v = fmaxf(v, sacc[kt2][qt2][r]);
            v = fmaxf(v, __shfl_xor(v, 16));
            v = fmaxf(v, __shfl_xor(v, 32));
            float mn = fmaxf(mreg[qt2], v);
            al[qt2] = exp2f((mreg[qt2] - mn) * L2E);
            mreg[qt2] = mn;
            float rs = 0.f;
#pragma unroll
            for (int kt2 = 0; kt2 < 2; ++kt2) {
                union { f16 h[4]; uint2 u; } pk;
#pragma unroll
                for (int r = 0; r < 4; ++r) {
                    float p = exp2f((sacc[kt2][qt2][r] - mn) * L2E);
                    rs += p;
                    pk.h[r] = (f16)p;
                }
                *(uint2*)&Pw[qt2 * 16 + n][kt2 * 16 + g * 4] = pk.u;
            }
            lsum[qt2] = lsum[qt2] * al[qt2] + rs;   // per-lane partial; reduced at end
        }
#pragma unroll
        for (int mtc = 0; mtc < 8; ++mtc)
#pragma unroll
            for (int qt2 = 0; qt2 < 2; ++qt2)
#pragma unroll
                for (int r = 0; r < 4; ++r) oacc[mtc][qt2][r] *= al[qt2];

        // phase B: O^T[c][q] += V.P^T  (A=V[c][key], B=P[q][key]; one K=32 chunk)
        {
            f16x8 pf[2];
#pragma unroll
            for (int qt2 = 0; qt2 < 2; ++qt2) pf[qt2] = *(const f16x8*)&Pw[qt2 * 16 + n][g * 8];
#pragma unroll
            for (int mtc = 0; mtc < 8; ++mtc) {
                f16x8 vf = *(const f16x8*)&Vl[mtc * 16 + n][g * 8];
#pragma unroll
                for (int qt2 = 0; qt2 < 2; ++qt2)
                    oacc[mtc][qt2] = __builtin_amdgcn_mfma_f32_16x16x32_f16(vf, pf[qt2], oacc[mtc][qt2], 0, 0, 0);
            }
        }
    }

    // final l reduction over g-lanes
    float lreg[2];
#pragma unroll
    for (int qt2 = 0; qt2 < 2; ++qt2) {
        float s = lsum[qt2];
        s += __shfl_xor(s, 16);
        s += __shfl_xor(s, 32);
        lreg[qt2] = s;
    }

    const int pidx = (b * 32 + qt) * 8 + kh;
    if (g == 0) {
        float* MlW = Ml + (size_t)pidx * 256;
#pragma unroll
        for (int qt2 = 0; qt2 < 2; ++qt2) {
            int q = w * 32 + qt2 * 16 + n;
            MlW[q]       = mreg[qt2];
            MlW[128 + q] = lreg[qt2];
        }
    }

    // epilogue: transpose O^T frags through LDS (reuse arena), coalesced store
    __syncthreads();                            // all phase-B reads done
    f16 (*S2)[136] = (f16(*)[136])arena;        // [128 c][128 q] = 34816 B (fits arena)
#pragma unroll
    for (int mtc = 0; mtc < 8; ++mtc)
#pragma unroll
        for (int qt2 = 0; qt2 < 2; ++qt2)
#pragma unroll
            for (int r = 0; r < 4; ++r)
                S2[mtc * 16 + g * 4 + r][w * 32 + qt2 * 16 + n] = (f16)oacc[mtc][qt2][r];
    __syncthreads();
    f16* OpW = Op + (size_t)pidx * 16384;
#pragma unroll
    for (int i = 0; i < 8; ++i) {
        int vi = tid + i * 256;                 // 0..2047
        int c = vi >> 4, qq = (vi & 15) * 8;
        *(uint4*)&OpW[c * 128 + qq] = *(const uint4*)&S2[c][qq];
    }
}

// ---------------------------------------------------------------- merge (8 partials)
__global__ __launch_bounds__(256) void mrgk(
    const f16* __restrict__ Op, const float* __restrict__ Ml,
    const float* __restrict__ xv, const float* __restrict__ gp, const float* __restrict__ bp,
    float* __restrict__ out)
{
    const int bx = blockIdx.x;                 // (b*32+qt)*4 + cg
    const int cg = bx & 3, bqt = bx >> 2;
    const int b = bqt >> 5, qt = bqt & 31;
    const int tid = threadIdx.x;
    const int q = tid & 127, hf = tid >> 7;

    const float* ml = Ml + (size_t)bqt * 8 * 256;
    float m = -1e30f;
#pragma unroll
    for (int k2 = 0; k2 < 8; ++k2) m = fmaxf(m, ml[k2 * 256 + q]);
    float wt[8], tot = 0.f;
#pragma unroll
    for (int k2 = 0; k2 < 8; ++k2) {
        wt[k2] = exp2f((ml[k2 * 256 + q] - m) * L2E);
        tot += wt[k2] * ml[k2 * 256 + 128 + q];
    }
    float inv = 1.f / tot;
    float gm = gp[0], bb = bp[0];

    const f16* O = Op + (size_t)bqt * 8 * 16384;
#pragma unroll 2
    for (int i = 0; i < 16; ++i) {
        int c = cg * 32 + hf * 16 + i;
        float o = 0.f;
#pragma unroll
        for (int k2 = 0; k2 < 8; ++k2) o += wt[k2] * (float)O[k2 * 16384 + c * 128 + q];
        o *= inv;
        size_t idx = ((size_t)(b * CC + c)) * SS + qt * 128 + q;
        out[idx] = gm * o + bb * xv[idx];
    }
}

// ---------------------------------------------------------------- launcher
extern "C" void kernel_launch(void* const* d_in, const int* in_sizes, int n_in,
                              void* d_out, int out_size, void* d_ws, size_t ws_size,
                              hipStream_t stream) {
    (void)in_sizes; (void)n_in; (void)out_size; (void)ws_size;

    const size_t TEN = (size_t)4 * SS * CC;          // 2,097,152
    f16* Qt = (f16*)d_ws;                            // 4 MB
    f16* Kt = Qt + TEN;                              // 4 MB
    f16* Vt = Kt + TEN;                              // 4 MB (channel-major)
    f16* Op = Vt + TEN;                              // 1024*16384 f16 = 32 MB
    float* Ml = (float*)(Op + (size_t)1024 * 16384); // 1 MB

    PArg aq = { (const float*)d_in[0], (const float*)d_in[3],  (const float*)d_in[4],
                (const float*)d_in[5], (const float*)d_in[6],  (const float*)d_in[7],
                (const float*)d_in[8],  Qt };
    PArg ak = { (const float*)d_in[1], (const float*)d_in[9],  (const float*)d_in[10],
                (const float*)d_in[11], (const float*)d_in[12], (const float*)d_in[13],
                (const float*)d_in[14], Kt };
    PArg av = { (const float*)d_in[2], (const float*)d_in[15], (const float*)d_in[16],
                (const float*)d_in[17], (const float*)d_in[18], (const float*)d_in[19],
                (const float*)d_in[20], Vt };

    hipLaunchKernelGGL(projk, dim3(256, 3), dim3(256), 0, stream, aq, ak, av);
    hipLaunchKernelGGL(attnk, dim3(1024), dim3(256), 0, stream, Qt, Kt, Vt, Op, Ml);
    hipLaunchKernelGGL(mrgk, dim3(512), dim3(256), 0, stream,
                       Op, Ml, (const float*)d_in[2], (const float*)d_in[21],
                       (const float*)d_in[22], (float*)d_out);
}